// Round 1
// baseline (1041.077 us; speedup 1.0000x reference)
//
#include <hip/hip_runtime.h>

#define NN 50000
#define NF 256
#define NH 256
#define NC 40
#define NE 800000

// ---------------- preprocessing ----------------

__global__ void count_kernel(const int* __restrict__ dst, int* __restrict__ cnt) {
  int e = blockIdx.x * blockDim.x + threadIdx.x;
  if (e < NE) atomicAdd(&cnt[dst[e]], 1);
}

__global__ void dis_kernel(const int* __restrict__ cnt, float* __restrict__ dis) {
  int i = blockIdx.x * blockDim.x + threadIdx.x;
  if (i < NN) dis[i] = rsqrtf((float)(cnt[i] + 1));  // +1 self-loop
}

// single-block exclusive scan of cnt[0..NN) -> row_ptr[0..NN]
__global__ void scan_kernel(const int* __restrict__ cnt, int* __restrict__ row_ptr) {
  __shared__ int sdata[1024];
  int carry = 0;
  for (int base = 0; base < NN; base += 1024) {
    int i = base + threadIdx.x;
    int v = (i < NN) ? cnt[i] : 0;
    sdata[threadIdx.x] = v;
    __syncthreads();
    for (int ofs = 1; ofs < 1024; ofs <<= 1) {
      int t = (threadIdx.x >= ofs) ? sdata[threadIdx.x - ofs] : 0;
      __syncthreads();
      sdata[threadIdx.x] += t;
      __syncthreads();
    }
    int incl = sdata[threadIdx.x];
    if (i < NN) row_ptr[i] = carry + incl - v;  // exclusive
    __syncthreads();
    carry += sdata[1023];
    __syncthreads();
  }
  if (threadIdx.x == 0) row_ptr[NN] = carry;
}

__global__ void scatter_kernel(const int* __restrict__ src, const int* __restrict__ dst,
                               const int* __restrict__ row_ptr, int* __restrict__ cur,
                               int* __restrict__ src_sorted, float* __restrict__ wnorm,
                               const float* __restrict__ dis) {
  int e = blockIdx.x * blockDim.x + threadIdx.x;
  if (e < NE) {
    int d = dst[e], s = src[e];
    int pos = row_ptr[d] + atomicAdd(&cur[d], 1);
    src_sorted[pos] = s;
    wnorm[pos] = dis[s] * dis[d];
  }
}

// ---------------- fp32 tiled GEMM: C[M,Ncols] = A[M,NF] * B[NF,Ncols] ----------------

#define BM 64
#define BN 64
#define BK 16

__global__ __launch_bounds__(256) void gemm_kernel(const float* __restrict__ A,
                                                   const float* __restrict__ B,
                                                   float* __restrict__ C,
                                                   int M, int Ncols) {
  __shared__ float As[BK][BM + 4];
  __shared__ float Bs[BK][BN + 4];
  int tid = threadIdx.x;
  int tx = tid & 15, ty = tid >> 4;
  int rowBase = blockIdx.x * BM;
  int colBase = blockIdx.y * BN;
  float acc[4][4] = {};
  for (int k0 = 0; k0 < NF; k0 += BK) {
#pragma unroll
    for (int l = 0; l < 4; ++l) {
      int idx = tid + l * 256;
      int r = idx >> 4, k = idx & 15;
      int gr = rowBase + r;
      As[k][r] = (gr < M) ? A[gr * NF + k0 + k] : 0.0f;
    }
#pragma unroll
    for (int l = 0; l < 4; ++l) {
      int idx = tid + l * 256;
      int k = idx >> 6, c = idx & 63;
      int gc = colBase + c;
      Bs[k][c] = (gc < Ncols) ? B[(k0 + k) * Ncols + gc] : 0.0f;
    }
    __syncthreads();
#pragma unroll
    for (int k = 0; k < BK; ++k) {
      float a[4], b[4];
#pragma unroll
      for (int i = 0; i < 4; ++i) a[i] = As[k][ty * 4 + i];
#pragma unroll
      for (int j = 0; j < 4; ++j) b[j] = Bs[k][tx * 4 + j];
#pragma unroll
      for (int i = 0; i < 4; ++i)
#pragma unroll
        for (int j = 0; j < 4; ++j) acc[i][j] += a[i] * b[j];
    }
    __syncthreads();
  }
#pragma unroll
  for (int i = 0; i < 4; ++i) {
    int gr = rowBase + ty * 4 + i;
    if (gr < M) {
#pragma unroll
      for (int j = 0; j < 4; ++j) {
        int gc = colBase + tx * 4 + j;
        if (gc < Ncols) C[gr * Ncols + gc] = acc[i][j];
      }
    }
  }
}

// ---------------- aggregation: one wave per node ----------------

__global__ __launch_bounds__(256) void agg256_kernel(
    const float* __restrict__ T, float* __restrict__ H, const int* __restrict__ rp,
    const int* __restrict__ ss, const float* __restrict__ wn,
    const float* __restrict__ dis, const float* __restrict__ b, int relu) {
  int node = (blockIdx.x * blockDim.x + threadIdx.x) >> 6;
  int lane = threadIdx.x & 63;
  if (node >= NN) return;
  const float4* Tv = (const float4*)T;
  float4 bv = ((const float4*)b)[lane];
  float d = dis[node];
  float w0 = d * d;
  float4 t = Tv[node * 64 + lane];
  float ax = bv.x + w0 * t.x, ay = bv.y + w0 * t.y;
  float az = bv.z + w0 * t.z, aw = bv.w + w0 * t.w;
  int beg = rp[node], end = rp[node + 1];
  for (int e = beg; e < end; ++e) {
    float w = wn[e];
    float4 ts = Tv[ss[e] * 64 + lane];
    ax += w * ts.x; ay += w * ts.y; az += w * ts.z; aw += w * ts.w;
  }
  if (relu) {
    ax = fmaxf(ax, 0.f); ay = fmaxf(ay, 0.f);
    az = fmaxf(az, 0.f); aw = fmaxf(aw, 0.f);
  }
  float4 o; o.x = ax; o.y = ay; o.z = az; o.w = aw;
  ((float4*)H)[node * 64 + lane] = o;
}

__global__ __launch_bounds__(256) void agg40_kernel(
    const float* __restrict__ T, float* __restrict__ O, const int* __restrict__ rp,
    const int* __restrict__ ss, const float* __restrict__ wn,
    const float* __restrict__ dis, const float* __restrict__ b) {
  int node = (blockIdx.x * blockDim.x + threadIdx.x) >> 6;
  int lane = threadIdx.x & 63;
  if (node >= NN) return;
  float d = dis[node];
  int beg = rp[node], end = rp[node + 1];
  if (lane < NC) {
    float acc = b[lane] + d * d * T[node * NC + lane];
    for (int e = beg; e < end; ++e) {
      acc += wn[e] * T[ss[e] * NC + lane];
    }
    O[node * NC + lane] = acc;
  }
}

// ---------------- launch ----------------

extern "C" void kernel_launch(void* const* d_in, const int* in_sizes, int n_in,
                              void* d_out, int out_size, void* d_ws, size_t ws_size,
                              hipStream_t stream) {
  const float* x  = (const float*)d_in[0];
  const int*  edge = (const int*)d_in[1];   // [2, NE], int32 (jax x64 disabled)
  const float* W1 = (const float*)d_in[2];
  const float* b1 = (const float*)d_in[3];
  const float* W2 = (const float*)d_in[4];
  const float* b2 = (const float*)d_in[5];
  const float* W3 = (const float*)d_in[6];
  const float* b3 = (const float*)d_in[7];
  const float* W4 = (const float*)d_in[8];
  const float* b4 = (const float*)d_in[9];
  float* out = (float*)d_out;

  char* p = (char*)d_ws;
  float* T = (float*)p;            p += (size_t)NN * NH * 4;   // 51.2 MB
  float* H = (float*)p;            p += (size_t)NN * NH * 4;   // 51.2 MB
  int* cnt = (int*)p;              p += (size_t)NN * 4;
  float* dis = (float*)p;          p += (size_t)NN * 4;
  int* row_ptr = (int*)p;          p += (size_t)(NN + 16) * 4;
  int* cur = (int*)p;              p += (size_t)NN * 4;
  int* src_sorted = (int*)p;       p += (size_t)NE * 4;
  float* wnorm = (float*)p;        p += (size_t)NE * 4;

  const int* e_src = edge;
  const int* e_dst = edge + NE;

  hipMemsetAsync(cnt, 0, (size_t)NN * 4, stream);
  hipMemsetAsync(cur, 0, (size_t)NN * 4, stream);

  count_kernel<<<(NE + 255) / 256, 256, 0, stream>>>(e_dst, cnt);
  dis_kernel<<<(NN + 255) / 256, 256, 0, stream>>>(cnt, dis);
  scan_kernel<<<1, 1024, 0, stream>>>(cnt, row_ptr);
  scatter_kernel<<<(NE + 255) / 256, 256, 0, stream>>>(e_src, e_dst, row_ptr, cur,
                                                       src_sorted, wnorm, dis);

  dim3 g1((NN + BM - 1) / BM, (NH + BN - 1) / BN);
  dim3 g4((NN + BM - 1) / BM, (NC + BN - 1) / BN);
  int aggBlocks = (NN * 64 + 255) / 256;

  // layer 1
  gemm_kernel<<<g1, 256, 0, stream>>>(x, W1, T, NN, NH);
  agg256_kernel<<<aggBlocks, 256, 0, stream>>>(T, H, row_ptr, src_sorted, wnorm, dis, b1, 1);
  // layer 2
  gemm_kernel<<<g1, 256, 0, stream>>>(H, W2, T, NN, NH);
  agg256_kernel<<<aggBlocks, 256, 0, stream>>>(T, H, row_ptr, src_sorted, wnorm, dis, b2, 1);
  // layer 3
  gemm_kernel<<<g1, 256, 0, stream>>>(H, W3, T, NN, NH);
  agg256_kernel<<<aggBlocks, 256, 0, stream>>>(T, H, row_ptr, src_sorted, wnorm, dis, b3, 1);
  // layer 4 (256 -> 40, no relu)
  gemm_kernel<<<g4, 256, 0, stream>>>(H, W4, T, NN, NC);
  agg40_kernel<<<aggBlocks, 256, 0, stream>>>(T, out, row_ptr, src_sorted, wnorm, dis, b4);
}

// Round 2
// 751.683 us; speedup vs baseline: 1.3850x; 1.3850x over previous
//
#include <hip/hip_runtime.h>

#define NN 50000
#define NF 256
#define NH 256
#define NC 40
#define NE 800000

typedef short bf16x8 __attribute__((ext_vector_type(8)));
typedef float f32x4 __attribute__((ext_vector_type(4)));

__device__ __forceinline__ unsigned short bf16_rn(float f) {
  union { float f; unsigned u; } a; a.f = f;
  unsigned r = ((a.u >> 16) & 1u) + 0x7FFFu;
  return (unsigned short)((a.u + r) >> 16);
}
__device__ __forceinline__ float bf16f(unsigned short h) {
  union { unsigned u; float f; } a; a.u = ((unsigned)h) << 16;
  return a.f;
}

__device__ __forceinline__ void gl16(const void* g, void* l) {
  __builtin_amdgcn_global_load_lds(
      (const __attribute__((address_space(1))) unsigned int*)g,
      (__attribute__((address_space(3))) unsigned int*)l, 16, 0, 0);
}

// ---------------- preprocessing ----------------

__global__ void count_kernel(const int* __restrict__ dst, int* __restrict__ cnt) {
  int e = blockIdx.x * blockDim.x + threadIdx.x;
  if (e < NE) atomicAdd(&cnt[dst[e]], 1);
}

__global__ void dis_kernel(const int* __restrict__ cnt, float* __restrict__ dis) {
  int i = blockIdx.x * blockDim.x + threadIdx.x;
  if (i < NN) dis[i] = rsqrtf((float)(cnt[i] + 1));
}

__global__ void scan_kernel(const int* __restrict__ cnt, int* __restrict__ row_ptr) {
  __shared__ int sdata[1024];
  int carry = 0;
  for (int base = 0; base < NN; base += 1024) {
    int i = base + threadIdx.x;
    int v = (i < NN) ? cnt[i] : 0;
    sdata[threadIdx.x] = v;
    __syncthreads();
    for (int ofs = 1; ofs < 1024; ofs <<= 1) {
      int t = (threadIdx.x >= ofs) ? sdata[threadIdx.x - ofs] : 0;
      __syncthreads();
      sdata[threadIdx.x] += t;
      __syncthreads();
    }
    int incl = sdata[threadIdx.x];
    if (i < NN) row_ptr[i] = carry + incl - v;
    __syncthreads();
    carry += sdata[1023];
    __syncthreads();
  }
  if (threadIdx.x == 0) row_ptr[NN] = carry;
}

__global__ void scatter_kernel(const int* __restrict__ src, const int* __restrict__ dst,
                               const int* __restrict__ row_ptr, int* __restrict__ cur,
                               int* __restrict__ src_sorted, float* __restrict__ wnorm,
                               const float* __restrict__ dis) {
  int e = blockIdx.x * blockDim.x + threadIdx.x;
  if (e < NE) {
    int d = dst[e], s = src[e];
    int pos = row_ptr[d] + atomicAdd(&cur[d], 1);
    src_sorted[pos] = s;
    wnorm[pos] = dis[s] * dis[d];
  }
}

// ---------------- conversions ----------------

// split 12.8M floats into bf16 hi/lo planes, 4 at a time
__global__ __launch_bounds__(256) void split_kernel(const float* __restrict__ x,
                                                    unsigned short* __restrict__ hi,
                                                    unsigned short* __restrict__ lo) {
  int i = blockIdx.x * blockDim.x + threadIdx.x;
  if (i >= NN * NF / 4) return;
  float4 v = ((const float4*)x)[i];
  ushort4 h, l;
  h.x = bf16_rn(v.x); l.x = bf16_rn(v.x - bf16f(h.x));
  h.y = bf16_rn(v.y); l.y = bf16_rn(v.y - bf16f(h.y));
  h.z = bf16_rn(v.z); l.z = bf16_rn(v.z - bf16f(h.z));
  h.w = bf16_rn(v.w); l.w = bf16_rn(v.w - bf16f(h.w));
  ((ushort4*)hi)[i] = h;
  ((ushort4*)lo)[i] = l;
}

// W[K=256][N] -> Wt hi/lo [NT][256], zero-padded rows n>=N
__global__ void wsplit_kernel(const float* __restrict__ W,
                              unsigned short* __restrict__ Whi,
                              unsigned short* __restrict__ Wlo, int N, int NT) {
  int idx = blockIdx.x * blockDim.x + threadIdx.x;
  if (idx >= NT * 256) return;
  int n = idx >> 8, k = idx & 255;
  float v = (n < N) ? W[k * N + n] : 0.0f;
  unsigned short h = bf16_rn(v);
  Whi[idx] = h;
  Wlo[idx] = bf16_rn(v - bf16f(h));
}

// ---------------- split-bf16 MFMA GEMM: C[M][OUTSTRIDE] = A[M][256] * Bt[*][256]^T ----------------
// A planes: [M][256] bf16 hi/lo. Bt planes: [>=colBase+128][256] bf16 hi/lo (B transposed).
// Tile 128x128, BK=64, 4 waves in 2x2. XOR-swizzled LDS (16B granule ^ (row&7)).

template <int NSTORE, int OUTSTRIDE>
__global__ __launch_bounds__(256, 2) void gemm_mfma(
    const unsigned short* __restrict__ Ahi, const unsigned short* __restrict__ Alo,
    const unsigned short* __restrict__ Bthi, const unsigned short* __restrict__ Btlo,
    float* __restrict__ C, int M) {
  __shared__ unsigned short lds[4][128 * 64];  // Ahi, Alo, Bhi, Blo tiles (16 KB each)

  int tid = threadIdx.x;
  int rowBase = blockIdx.x * 128;
  int colBase = blockIdx.y * 128;
  int w = tid >> 6, lane = tid & 63;
  int wr = w >> 1, wc = w & 1;
  int l15 = lane & 15, l4 = lane >> 4;

  f32x4 acc[4][4] = {};

  for (int kt = 0; kt < 4; ++kt) {
    // ---- stage: 4 planes x 16KB, pre-swizzled global source, linear LDS dest ----
#pragma unroll
    for (int c = 0; c < 4; ++c) {
      int gi = c * 256 + tid;          // 16B granule index
      int row = gi >> 3, gp = gi & 7;  // lds (row, granule)
      int gsrc = gp ^ (row & 7);       // source k-granule
      int ar = rowBase + row; ar = ar < M ? ar : M - 1;
      int koff = kt * 64 + gsrc * 8;
      gl16(Ahi + (size_t)ar * 256 + koff, &lds[0][gi * 8]);
      gl16(Alo + (size_t)ar * 256 + koff, &lds[1][gi * 8]);
      int br = colBase + row;
      gl16(Bthi + (size_t)br * 256 + koff, &lds[2][gi * 8]);
      gl16(Btlo + (size_t)br * 256 + koff, &lds[3][gi * 8]);
    }
    __syncthreads();

#pragma unroll
    for (int ks = 0; ks < 2; ++ks) {
      bf16x8 ah[4], al[4], bh[4], bl[4];
      int g = ks * 4 + l4;
#pragma unroll
      for (int mi = 0; mi < 4; ++mi) {
        int row = wr * 64 + mi * 16 + l15;
        int gp = g ^ (row & 7);
        ah[mi] = *(const bf16x8*)&lds[0][row * 64 + gp * 8];
        al[mi] = *(const bf16x8*)&lds[1][row * 64 + gp * 8];
      }
#pragma unroll
      for (int ni = 0; ni < 4; ++ni) {
        int row = wc * 64 + ni * 16 + l15;
        int gp = g ^ (row & 7);
        bh[ni] = *(const bf16x8*)&lds[2][row * 64 + gp * 8];
        bl[ni] = *(const bf16x8*)&lds[3][row * 64 + gp * 8];
      }
#pragma unroll
      for (int mi = 0; mi < 4; ++mi)
#pragma unroll
        for (int ni = 0; ni < 4; ++ni) {
          acc[mi][ni] = __builtin_amdgcn_mfma_f32_16x16x32_bf16(ah[mi], bh[ni], acc[mi][ni], 0, 0, 0);
          acc[mi][ni] = __builtin_amdgcn_mfma_f32_16x16x32_bf16(al[mi], bh[ni], acc[mi][ni], 0, 0, 0);
          acc[mi][ni] = __builtin_amdgcn_mfma_f32_16x16x32_bf16(ah[mi], bl[ni], acc[mi][ni], 0, 0, 0);
        }
    }
    __syncthreads();
  }

  // epilogue: D row=(lane>>4)*4+i, col=lane&15 (m89 layout)
#pragma unroll
  for (int ni = 0; ni < 4; ++ni) {
    int col = colBase + wc * 64 + ni * 16 + l15;
    if (col < NSTORE) {
#pragma unroll
      for (int mi = 0; mi < 4; ++mi) {
        f32x4 v = acc[mi][ni];
#pragma unroll
        for (int i = 0; i < 4; ++i) {
          int r = rowBase + wr * 64 + mi * 16 + l4 * 4 + i;
          if (r < M) C[(size_t)r * OUTSTRIDE + col] = v[i];
        }
      }
    }
  }
}

// ---------------- aggregation: one wave per node ----------------

__global__ __launch_bounds__(256) void agg256_kernel(
    const float* __restrict__ T, unsigned short* __restrict__ Phi,
    unsigned short* __restrict__ Plo, const int* __restrict__ rp,
    const int* __restrict__ ss, const float* __restrict__ wn,
    const float* __restrict__ dis, const float* __restrict__ b) {
  int node = (blockIdx.x * blockDim.x + threadIdx.x) >> 6;
  int lane = threadIdx.x & 63;
  if (node >= NN) return;
  const float4* Tv = (const float4*)T;
  float4 bv = ((const float4*)b)[lane];
  float d = dis[node];
  float w0 = d * d;
  float4 t = Tv[node * 64 + lane];
  float ax = bv.x + w0 * t.x, ay = bv.y + w0 * t.y;
  float az = bv.z + w0 * t.z, aw = bv.w + w0 * t.w;
  int beg = rp[node], end = rp[node + 1];
  for (int e = beg; e < end; ++e) {
    float w = wn[e];
    float4 ts = Tv[ss[e] * 64 + lane];
    ax += w * ts.x; ay += w * ts.y; az += w * ts.z; aw += w * ts.w;
  }
  ax = fmaxf(ax, 0.f); ay = fmaxf(ay, 0.f);
  az = fmaxf(az, 0.f); aw = fmaxf(aw, 0.f);
  ushort4 h, l;
  h.x = bf16_rn(ax); l.x = bf16_rn(ax - bf16f(h.x));
  h.y = bf16_rn(ay); l.y = bf16_rn(ay - bf16f(h.y));
  h.z = bf16_rn(az); l.z = bf16_rn(az - bf16f(h.z));
  h.w = bf16_rn(aw); l.w = bf16_rn(aw - bf16f(h.w));
  ((ushort4*)Phi)[node * 64 + lane] = h;
  ((ushort4*)Plo)[node * 64 + lane] = l;
}

__global__ __launch_bounds__(256) void agg40_kernel(
    const float* __restrict__ T, float* __restrict__ O, const int* __restrict__ rp,
    const int* __restrict__ ss, const float* __restrict__ wn,
    const float* __restrict__ dis, const float* __restrict__ b) {
  int node = (blockIdx.x * blockDim.x + threadIdx.x) >> 6;
  int lane = threadIdx.x & 63;
  if (node >= NN) return;
  float d = dis[node];
  int beg = rp[node], end = rp[node + 1];
  if (lane < NC) {
    float acc = b[lane] + d * d * T[node * NC + lane];
    for (int e = beg; e < end; ++e) {
      acc += wn[e] * T[ss[e] * NC + lane];
    }
    O[node * NC + lane] = acc;
  }
}

// ---------------- launch ----------------

extern "C" void kernel_launch(void* const* d_in, const int* in_sizes, int n_in,
                              void* d_out, int out_size, void* d_ws, size_t ws_size,
                              hipStream_t stream) {
  const float* x  = (const float*)d_in[0];
  const int* edge = (const int*)d_in[1];
  const float* W1 = (const float*)d_in[2];
  const float* b1 = (const float*)d_in[3];
  const float* W2 = (const float*)d_in[4];
  const float* b2 = (const float*)d_in[5];
  const float* W3 = (const float*)d_in[6];
  const float* b3 = (const float*)d_in[7];
  const float* W4 = (const float*)d_in[8];
  const float* b4 = (const float*)d_in[9];
  float* out = (float*)d_out;

  char* p = (char*)d_ws;
  float* T = (float*)p;              p += (size_t)NN * NH * 4;   // 51.2 MB
  unsigned short* Phi = (unsigned short*)p; p += (size_t)NN * NH * 2;  // 25.6 MB
  unsigned short* Plo = (unsigned short*)p; p += (size_t)NN * NH * 2;  // 25.6 MB
  int* cnt = (int*)p;                p += (size_t)NN * 4;
  float* dis = (float*)p;            p += (size_t)NN * 4;
  int* row_ptr = (int*)p;            p += (size_t)(NN + 16) * 4;
  int* cur = (int*)p;                p += (size_t)NN * 4;
  int* src_sorted = (int*)p;         p += (size_t)NE * 4;
  float* wnorm = (float*)p;          p += (size_t)NE * 4;
  unsigned short* W1thi = (unsigned short*)p; p += 256 * 256 * 2;
  unsigned short* W1tlo = (unsigned short*)p; p += 256 * 256 * 2;
  unsigned short* W2thi = (unsigned short*)p; p += 256 * 256 * 2;
  unsigned short* W2tlo = (unsigned short*)p; p += 256 * 256 * 2;
  unsigned short* W3thi = (unsigned short*)p; p += 256 * 256 * 2;
  unsigned short* W3tlo = (unsigned short*)p; p += 256 * 256 * 2;
  unsigned short* W4thi = (unsigned short*)p; p += 128 * 256 * 2;
  unsigned short* W4tlo = (unsigned short*)p; p += 128 * 256 * 2;

  const int* e_src = edge;
  const int* e_dst = edge + NE;

  hipMemsetAsync(cnt, 0, (size_t)NN * 4, stream);
  hipMemsetAsync(cur, 0, (size_t)NN * 4, stream);

  count_kernel<<<(NE + 255) / 256, 256, 0, stream>>>(e_dst, cnt);
  dis_kernel<<<(NN + 255) / 256, 256, 0, stream>>>(cnt, dis);
  scan_kernel<<<1, 1024, 0, stream>>>(cnt, row_ptr);
  scatter_kernel<<<(NE + 255) / 256, 256, 0, stream>>>(e_src, e_dst, row_ptr, cur,
                                                       src_sorted, wnorm, dis);

  split_kernel<<<(NN * NF / 4 + 255) / 256, 256, 0, stream>>>(x, Phi, Plo);
  wsplit_kernel<<<256, 256, 0, stream>>>(W1, W1thi, W1tlo, NH, 256);
  wsplit_kernel<<<256, 256, 0, stream>>>(W2, W2thi, W2tlo, NH, 256);
  wsplit_kernel<<<256, 256, 0, stream>>>(W3, W3thi, W3tlo, NH, 256);
  wsplit_kernel<<<128, 256, 0, stream>>>(W4, W4thi, W4tlo, NC, 128);

  dim3 gFull((NN + 127) / 128, 2);
  dim3 gLast((NN + 127) / 128, 1);
  int aggBlocks = (NN * 64 + 255) / 256;

  gemm_mfma<256, 256><<<gFull, 256, 0, stream>>>(Phi, Plo, W1thi, W1tlo, T, NN);
  agg256_kernel<<<aggBlocks, 256, 0, stream>>>(T, Phi, Plo, row_ptr, src_sorted, wnorm, dis, b1);
  gemm_mfma<256, 256><<<gFull, 256, 0, stream>>>(Phi, Plo, W2thi, W2tlo, T, NN);
  agg256_kernel<<<aggBlocks, 256, 0, stream>>>(T, Phi, Plo, row_ptr, src_sorted, wnorm, dis, b2);
  gemm_mfma<256, 256><<<gFull, 256, 0, stream>>>(Phi, Plo, W3thi, W3tlo, T, NN);
  agg256_kernel<<<aggBlocks, 256, 0, stream>>>(T, Phi, Plo, row_ptr, src_sorted, wnorm, dis, b3);
  gemm_mfma<NC, NC><<<gLast, 256, 0, stream>>>(Phi, Plo, W4thi, W4tlo, T, NN);
  agg40_kernel<<<aggBlocks, 256, 0, stream>>>(T, out, row_ptr, src_sorted, wnorm, dis, b4);
}